// Round 1
// baseline (1150.143 us; speedup 1.0000x reference)
//
#include <hip/hip_runtime.h>
#include <math.h>

// ---------------------------------------------------------------------------
// SparseInterpolatedExperts on MI355X
// Shapes: B=4, N=256, D=384, T=260, L=12, F1=1536, F2=384, M=8, H=4, Dh=96
// ---------------------------------------------------------------------------

#define NA_   7077888L     // L*F1*F2
#define NTOT_ 14155776L    // 2*NA_
enum { EPI_NONE = 0, EPI_BIAS = 1, EPI_PROJ = 2, EPI_BIAS_RESID = 3, EPI_BIAS_GELU = 4 };

__device__ __forceinline__ float gelu_tanh(float x) {
  // jax.nn.gelu default: approximate=True (tanh form)
  float x3 = x * x * x;
  float t = tanhf(0.7978845608028654f * (x + 0.044715f * x3));
  return 0.5f * x * (1.0f + t);
}

// ---------------------------------------------------------------------------
// Generic fp32 tiled GEMM: C = epi(A @ B (+bias) (*scale)), optional B^T,
// optional (b,h) batching via blockIdx.z with independent strides.
// BM=BN=64, BK=16, 256 threads, 4x4 per thread.
// ---------------------------------------------------------------------------
template <bool TRANSB, int EPI>
__global__ __launch_bounds__(256) void gemm_tile(
    const float* __restrict__ A, const float* __restrict__ Bm,
    const float* __restrict__ bias, const float* __restrict__ bias2,
    float* __restrict__ C,
    int M, int N, int K, int lda, int ldb, int ldc,
    long sAb, long sAh, long sBb, long sBh, long sCb, long sCh, int Hb,
    float scale) {
  int z = blockIdx.z;
  int zb = z / Hb, zh = z % Hb;
  const float* Ab = A + (long)zb * sAb + (long)zh * sAh;
  const float* Bb = Bm + (long)zb * sBb + (long)zh * sBh;
  float* Cb = C + (long)zb * sCb + (long)zh * sCh;

  __shared__ float As[16][68];  // [k][m], stride 68 keeps float4 reads 16B-aligned
  __shared__ float Bs[16][68];  // [k][n]
  int tid = threadIdx.x;
  int tx = tid & 15, ty = tid >> 4;
  int m0 = blockIdx.x * 64, n0 = blockIdx.y * 64;

  float acc[4][4] = {};
  for (int k0 = 0; k0 < K; k0 += 16) {
    {  // A tile: 64 rows x 16 cols, one float4 per thread, store transposed
      int r = tid >> 2, c = (tid & 3) << 2;
      int row = m0 + r, col = k0 + c;
      float4 v = {0.f, 0.f, 0.f, 0.f};
      if (row < M && col < K) v = *(const float4*)(Ab + (long)row * lda + col);
      As[c + 0][r] = v.x; As[c + 1][r] = v.y; As[c + 2][r] = v.z; As[c + 3][r] = v.w;
    }
    if (!TRANSB) {  // B tile: 16 x 64, contiguous
      int r = tid >> 4, c = (tid & 15) << 2;
      int row = k0 + r, col = n0 + c;
      float4 v = {0.f, 0.f, 0.f, 0.f};
      if (row < K && col < N) v = *(const float4*)(Bb + (long)row * ldb + col);
      *(float4*)&Bs[r][c] = v;
    } else {  // B is N x K row-major (C = A @ B^T)
      int r = tid >> 2, c = (tid & 3) << 2;
      int row = n0 + r, col = k0 + c;
      float4 v = {0.f, 0.f, 0.f, 0.f};
      if (row < N && col < K) v = *(const float4*)(Bb + (long)row * ldb + col);
      Bs[c + 0][r] = v.x; Bs[c + 1][r] = v.y; Bs[c + 2][r] = v.z; Bs[c + 3][r] = v.w;
    }
    __syncthreads();
#pragma unroll
    for (int kk = 0; kk < 16; kk++) {
      float4 av = *(const float4*)&As[kk][ty << 2];
      float4 bv = *(const float4*)&Bs[kk][tx << 2];
      float a[4] = {av.x, av.y, av.z, av.w};
      float b[4] = {bv.x, bv.y, bv.z, bv.w};
#pragma unroll
      for (int i = 0; i < 4; i++)
#pragma unroll
        for (int j = 0; j < 4; j++) acc[i][j] = fmaf(a[i], b[j], acc[i][j]);
    }
    __syncthreads();
  }
#pragma unroll
  for (int i = 0; i < 4; i++) {
    int row = m0 + (ty << 2) + i;
    if (row >= M) continue;
    long orow = row;
    if (EPI == EPI_PROJ) orow = (long)(row >> 8) * 260 + 4 + (row & 255);
#pragma unroll
    for (int j = 0; j < 4; j++) {
      int col = n0 + (tx << 2) + j;
      if (col >= N) continue;
      float v = acc[i][j] * scale;
      if (EPI == EPI_BIAS || EPI == EPI_BIAS_RESID || EPI == EPI_BIAS_GELU) v += bias[col];
      if (EPI == EPI_PROJ) v += bias[col] + bias2[col];
      long idx = orow * (long)ldc + col;
      if (EPI == EPI_BIAS_RESID) Cb[idx] += v;
      else if (EPI == EPI_BIAS_GELU) Cb[idx] = gelu_tanh(v);
      else Cb[idx] = v;
    }
  }
}

// tok[b, t, :] = skills[t, :] for t < 4
__global__ void skills_copy(const float* __restrict__ skills, float* __restrict__ tok) {
  int b = blockIdx.x >> 2, t = blockIdx.x & 3;
  int d = threadIdx.x;
  tok[((long)(b * 260 + t)) * 384 + d] = skills[t * 384 + d];
}

// row LayerNorm, D=384, 128 threads x 3 elements
__global__ __launch_bounds__(128) void ln_kernel(const float* __restrict__ x,
                                                 const float* __restrict__ g,
                                                 const float* __restrict__ b,
                                                 float* __restrict__ y) {
  long row = blockIdx.x;
  const float* xr = x + row * 384;
  int t = threadIdx.x;
  float v0 = xr[t], v1 = xr[t + 128], v2 = xr[t + 256];
  float s = v0 + v1 + v2;
  __shared__ float red[2];
#pragma unroll
  for (int o = 32; o > 0; o >>= 1) s += __shfl_xor(s, o);
  if ((t & 63) == 0) red[t >> 6] = s;
  __syncthreads();
  float mean = (red[0] + red[1]) * (1.0f / 384.0f);
  __syncthreads();
  float d0 = v0 - mean, d1 = v1 - mean, d2 = v2 - mean;
  float q = d0 * d0 + d1 * d1 + d2 * d2;
#pragma unroll
  for (int o = 32; o > 0; o >>= 1) q += __shfl_xor(q, o);
  if ((t & 63) == 0) red[t >> 6] = q;
  __syncthreads();
  float var = (red[0] + red[1]) * (1.0f / 384.0f);
  float rstd = rsqrtf(var + 1e-6f);
  float* yr = y + row * 384;
  yr[t]       = d0 * rstd * g[t]       + b[t];
  yr[t + 128] = d1 * rstd * g[t + 128] + b[t + 128];
  yr[t + 256] = d2 * rstd * g[t + 256] + b[t + 256];
}

// softmax over rows of length 260, one wave per row
__global__ __launch_bounds__(64) void softmax260(float* __restrict__ S) {
  long row = blockIdx.x;
  float* p = S + row * 260;
  int l = threadIdx.x;
  float v0 = p[l], v1 = p[l + 64], v2 = p[l + 128], v3 = p[l + 192];
  float v4 = (l < 4) ? p[l + 256] : -INFINITY;
  float m = fmaxf(fmaxf(fmaxf(v0, v1), fmaxf(v2, v3)), v4);
#pragma unroll
  for (int o = 32; o > 0; o >>= 1) m = fmaxf(m, __shfl_xor(m, o));
  float e0 = __expf(v0 - m), e1 = __expf(v1 - m), e2 = __expf(v2 - m), e3 = __expf(v3 - m);
  float e4 = (l < 4) ? __expf(v4 - m) : 0.0f;
  float s = e0 + e1 + e2 + e3 + e4;
#pragma unroll
  for (int o = 32; o > 0; o >>= 1) s += __shfl_xor(s, o);
  float inv = 1.0f / s;
  p[l] = e0 * inv; p[l + 64] = e1 * inv; p[l + 128] = e2 * inv; p[l + 192] = e3 * inv;
  if (l < 4) p[l + 256] = e4 * inv;
}

// qtok = mean(tok[:, :4]); w = softmax(qtok @ mk^T / sqrt(384)); one block per b
__global__ __launch_bounds__(384) void qtokw(const float* __restrict__ tok,
                                             const float* __restrict__ mk,
                                             float* __restrict__ w) {
  int b = blockIdx.x;
  int d = threadIdx.x;
  __shared__ float qv[384];
  __shared__ float red[6];
  __shared__ float lgs[8];
  const float* base = tok + (long)b * 260 * 384;
  qv[d] = 0.25f * (base[d] + base[d + 384] + base[d + 768] + base[d + 1152]);
  __syncthreads();
  for (int m = 0; m < 8; m++) {
    float p = qv[d] * mk[m * 384 + d];
#pragma unroll
    for (int o = 32; o > 0; o >>= 1) p += __shfl_xor(p, o);
    if ((d & 63) == 0) red[d >> 6] = p;
    __syncthreads();
    if (d == 0) {
      float s = 0.f;
      for (int i = 0; i < 6; i++) s += red[i];
      lgs[m] = s * 0.05103103630798287f;  // 1/sqrt(384)
    }
    __syncthreads();
  }
  if (d == 0) {
    float mx = -INFINITY;
    for (int m = 0; m < 8; m++) mx = fmaxf(mx, lgs[m]);
    float s = 0.f, e[8];
    for (int m = 0; m < 8; m++) { e[m] = expf(lgs[m] - mx); s += e[m]; }
    for (int m = 0; m < 8; m++) w[b * 8 + m] = e[m] / s;
  }
}

// hard-concrete gate
__device__ __forceinline__ float hcz(float u, float la) {
  u = fminf(fmaxf(u, 1e-6f), 1.0f - 1e-6f);
  float lgt = __logf(u) - __logf(1.0f - u);       // log(u) - log1p(-u)
  float t = (lgt + la) * 1.5f;                    // / BETA, BETA = 2/3
  float e = __expf(-t);
  float s = __builtin_amdgcn_rcpf(1.0f + e);      // sigmoid
  return fminf(fmaxf(fmaf(s, 1.2f, -0.1f), 0.0f), 1.0f);  // *(zeta-gamma)+gamma, clip
}

// The big memory-bound kernel. 4 positions/thread; m (=8) is innermost so
// u/la reads are 2x float4 per position; output is float4 per b stream.
__global__ __launch_bounds__(256) void delta_kernel(
    const float* __restrict__ ua, const float* __restrict__ ub,
    const float* __restrict__ laa, const float* __restrict__ lab,
    const float* __restrict__ pa, const float* __restrict__ pb,
    const float* __restrict__ wv, float* __restrict__ out) {
  __shared__ float w[32];
  if (threadIdx.x < 32) w[threadIdx.x] = wv[threadIdx.x];
  __syncthreads();
  long p0 = ((long)blockIdx.x * 256 + threadIdx.x) * 4;
  const float *u, *la, *ph;
  long pp;
  if (p0 < NA_) { u = ua; la = laa; ph = pa; pp = p0; }
  else          { u = ub; la = lab; ph = pb; pp = p0 - NA_; }
  float4 phv = *(const float4*)(ph + pp);
  float pharr[4] = {phv.x, phv.y, phv.z, phv.w};
  float ob[4][4];
#pragma unroll
  for (int q = 0; q < 4; q++) {
    long base = (pp + q) * 8;
    float4 u0 = *(const float4*)(u + base);
    float4 u1 = *(const float4*)(u + base + 4);
    float4 l0 = *(const float4*)(la + base);
    float4 l1 = *(const float4*)(la + base + 4);
    float z[8];
    z[0] = hcz(u0.x, l0.x); z[1] = hcz(u0.y, l0.y); z[2] = hcz(u0.z, l0.z); z[3] = hcz(u0.w, l0.w);
    z[4] = hcz(u1.x, l1.x); z[5] = hcz(u1.y, l1.y); z[6] = hcz(u1.z, l1.z); z[7] = hcz(u1.w, l1.w);
#pragma unroll
    for (int bb = 0; bb < 4; bb++) {
      float s = 0.f;
#pragma unroll
      for (int mm = 0; mm < 8; mm++) s = fmaf(z[mm], w[bb * 8 + mm], s);
      ob[bb][q] = s * pharr[q];
    }
  }
#pragma unroll
  for (int bb = 0; bb < 4; bb++) {
    float4 v = make_float4(ob[bb][0], ob[bb][1], ob[bb][2], ob[bb][3]);
    *(float4*)(out + (long)bb * NTOT_ + p0) = v;
  }
}

// ---------------------------------------------------------------------------
extern "C" void kernel_launch(void* const* d_in, const int* in_sizes, int n_in,
                              void* d_out, int out_size, void* d_ws, size_t ws_size,
                              hipStream_t stream) {
  const float* x     = (const float*)d_in[0];
  const float* u_a   = (const float*)d_in[1];
  const float* u_b   = (const float*)d_in[2];
  const float* phi_a = (const float*)d_in[3];
  const float* phi_b = (const float*)d_in[4];
  const float* la_a  = (const float*)d_in[5];
  const float* la_b  = (const float*)d_in[6];
  const float* Wp    = (const float*)d_in[7];
  const float* bp    = (const float*)d_in[8];
  const float* skills= (const float*)d_in[9];
  const float* cenc  = (const float*)d_in[10];
  const float* ln1g  = (const float*)d_in[11];
  const float* ln1b  = (const float*)d_in[12];
  const float* Wqkv  = (const float*)d_in[13];
  const float* bqkv  = (const float*)d_in[14];
  const float* Wo    = (const float*)d_in[15];
  const float* bo    = (const float*)d_in[16];
  const float* ln2g  = (const float*)d_in[17];
  const float* ln2b  = (const float*)d_in[18];
  const float* W1    = (const float*)d_in[19];
  const float* b1    = (const float*)d_in[20];
  const float* W2    = (const float*)d_in[21];
  const float* b2    = (const float*)d_in[22];
  const float* mk    = (const float*)d_in[23];
  float* out = (float*)d_out;

  // workspace layout (floats), all offsets 16B-aligned
  float* tok = (float*)d_ws;        // 1040 x 384
  float* yb  = tok + 399360;        // 1040 x 384
  float* qkv = yb  + 399360;        // 1040 x 1152
  float* S   = qkv + 1198080;       // 16 x 260 x 260
  float* o   = S   + 1081600;       // 1040 x 384
  float* g   = o   + 399360;        // 1040 x 768
  float* wv  = g   + 798720;        // 32

  // 1) tok assembly: skill rows + (x @ Wp + bp + count_enc) remapped to rows 4..259
  skills_copy<<<dim3(16), dim3(384), 0, stream>>>(skills, tok);
  gemm_tile<false, EPI_PROJ><<<dim3(16, 6, 1), dim3(256), 0, stream>>>(
      x, Wp, bp, cenc, tok, 1024, 384, 384, 384, 384, 384, 0, 0, 0, 0, 0, 0, 1, 1.0f);
  // 2) LN1
  ln_kernel<<<dim3(1040), dim3(128), 0, stream>>>(tok, ln1g, ln1b, yb);
  // 3) qkv
  gemm_tile<false, EPI_BIAS><<<dim3(17, 18, 1), dim3(256), 0, stream>>>(
      yb, Wqkv, bqkv, nullptr, qkv, 1040, 1152, 384, 384, 1152, 1152, 0, 0, 0, 0, 0, 0, 1, 1.0f);
  // 4) scores = q @ k^T / sqrt(96), batched over (b,h)
  gemm_tile<true, EPI_NONE><<<dim3(5, 5, 16), dim3(256), 0, stream>>>(
      qkv, qkv + 384, nullptr, nullptr, S, 260, 260, 96, 1152, 1152, 260,
      299520, 96, 299520, 96, 270400, 67600, 4, 0.10206207261596574f);
  // 5) softmax rows
  softmax260<<<dim3(4160), dim3(64), 0, stream>>>(S);
  // 6) o = att @ v, batched, written into (b,t,h*96+d) layout
  gemm_tile<false, EPI_NONE><<<dim3(5, 2, 16), dim3(256), 0, stream>>>(
      S, qkv + 768, nullptr, nullptr, o, 260, 96, 260, 260, 1152, 384,
      270400, 67600, 299520, 96, 99840, 96, 4, 1.0f);
  // 7) tok += o @ Wo + bo
  gemm_tile<false, EPI_BIAS_RESID><<<dim3(17, 6, 1), dim3(256), 0, stream>>>(
      o, Wo, bo, nullptr, tok, 1040, 384, 384, 384, 384, 384, 0, 0, 0, 0, 0, 0, 1, 1.0f);
  // 8) LN2
  ln_kernel<<<dim3(1040), dim3(128), 0, stream>>>(tok, ln2g, ln2b, yb);
  // 9) g = gelu(y @ W1 + b1)
  gemm_tile<false, EPI_BIAS_GELU><<<dim3(17, 12, 1), dim3(256), 0, stream>>>(
      yb, W1, b1, nullptr, g, 1040, 768, 384, 384, 768, 768, 0, 0, 0, 0, 0, 0, 1, 1.0f);
  // 10) tok += g @ W2 + b2
  gemm_tile<false, EPI_BIAS_RESID><<<dim3(17, 6, 1), dim3(256), 0, stream>>>(
      g, W2, b2, nullptr, tok, 1040, 384, 768, 768, 384, 384, 0, 0, 0, 0, 0, 0, 1, 1.0f);
  // 11) w = softmax(mean(tok[:, :4]) @ mk^T / sqrt(D))
  qtokw<<<dim3(4), dim3(384), 0, stream>>>(tok, mk, wv);
  // 12) the memory-bound delta kernel
  delta_kernel<<<dim3(13824), dim3(256), 0, stream>>>(u_a, u_b, la_a, la_b, phi_a, phi_b, wv, out);
}